// Round 1
// baseline (221.199 us; speedup 1.0000x reference)
//
#include <hip/hip_runtime.h>
#include <math.h>

// out[b,s,d] = x[b,s,d] + pe[s,d];  x: fp32 [8, 4096, 1024]
// pe[s,d] = sin(s * 10000^(-2d/1024)) if d even else cos(...)
//
// R1: batch-amortized pe, latency-bound (2 TB/s, VALUBusy 5%) — serialized
//     8 ld/st per thread with only 32 VGPRs.
// R2: max-TLP structure but hand-written chain constants were wrong at 1e-5
//     rel — ×4000 rad phase amplification → absmax 0.133 (fail).
// R3: R2 structure + R1's per-element exp2f math (passed at 0.031 absmax),
//     220 µs = 1.22 TB/s — 5x off the 6.7 TB/s streaming roofline. libm
//     sinf/cosf software range-reduction (~40-60 VALU ops each at args up
//     to 4095 rad) made it VALU/latency-bound.
// R4 (this): hardware trig in revolutions. Fold 1/2pi into the exp2
//     exponent: rev = pos * exp2(c*d - log2(2pi)); range-reduce with
//     n=floor(rev), r=fma(pos,wr,-n) (exact-product fract — single rounding
//     at |r|<1, avoids losing 9 bits at rev~650); then v_sin_f32/v_cos_f32
//     (input in REVOLUTIONS, D=sin(2pi*S0)). ~30 VALU + 8 trans per thread.

#define PE_D 1024
#define PE_S 4096
#define PE_B 8

__global__ __launch_bounds__(256) void
PositionalEncoderModule_48455821033878_kernel(const float* __restrict__ x,
                                              float* __restrict__ out) {
    const int tid = blockIdx.x * blockDim.x + threadIdx.x;   // over B*S*D/4 = 8M
    const int d4  = tid & (PE_D / 4 - 1);                    // float4 index in row
    const int s   = (tid >> 8) & (PE_S - 1);                 // seq position
    const int d0  = d4 << 2;                                 // even

    // Issue the load first; pe math hides its latency.
    const size_t base = (size_t)tid * 4;
    const float4 v = *(const float4*)(x + base);

    const float pos = (float)s;
    // 10000^(-2d/1024) = exp2(c*d), c = -2*log2(1e4)/1024
    const float c = -0.025952563241307517f;
    // fold 1/(2pi) into the exponent: -log2(2*pi)
    const float L = -2.6514961294723187f;

    float pe[4];
#pragma unroll
    for (int j = 0; j < 4; ++j) {
        const float wr  = exp2f(fmaf(c, (float)(d0 + j), L)); // w_d / (2pi)
        const float rev = pos * wr;                           // phase in revolutions
        const float n   = floorf(rev);
        const float r   = fmaf(pos, wr, -n);                  // exact-product fract
        pe[j] = (j & 1) ? __builtin_amdgcn_cosf(r)            // odd  -> cos
                        : __builtin_amdgcn_sinf(r);           // even -> sin
    }

    float4 o;
    o.x = v.x + pe[0];
    o.y = v.y + pe[1];
    o.z = v.z + pe[2];
    o.w = v.w + pe[3];
    *(float4*)(out + base) = o;
}

extern "C" void kernel_launch(void* const* d_in, const int* in_sizes, int n_in,
                              void* d_out, int out_size, void* d_ws, size_t ws_size,
                              hipStream_t stream) {
    const float* x = (const float*)d_in[0];
    float* out     = (float*)d_out;

    const int n_threads = PE_B * PE_S * PE_D / 4;            // 8,388,608
    const int block = 256;
    const int grid  = n_threads / block;                     // 32768

    PositionalEncoderModule_48455821033878_kernel<<<grid, block, 0, stream>>>(x, out);
}

// Round 2
// 218.349 us; speedup vs baseline: 1.0131x; 1.0131x over previous
//
#include <hip/hip_runtime.h>
#include <math.h>

// out[b,s,d] = x[b,s,d] + pe[s,d];  x: fp32 [8, 4096, 1024]
// pe[s,d] = sin(s * 10000^(-2d/1024)) if d even else cos(...)
//
// R1: batch-amortized pe, latency-bound (2 TB/s, VALUBusy 5%) — serialized
//     8 ld/st per thread with only 32 VGPRs.
// R2: max-TLP structure but hand-written chain constants were wrong at 1e-5
//     rel — ×4000 rad phase amplification → absmax 0.133 (fail).
// R3: R2 structure + per-element exp2f + libm sinf/cosf (passed, 220 µs).
// R4: hw trig (v_sin/v_cos in revolutions, exact-product fract) — dur_us
//     unchanged (221 µs) => kernel is NOT VALU-bound. Also: kernel absent
//     from duration-sorted top-5 (all ~80µs re-poison fills) => kernel
//     itself is <80 µs; dur_us ≈ 2×80.5 µs harness fills + ~59 µs kernel.
// R5 (this): memory-side polish only. 2 independent float4 loads/thread
//     (2× bytes in flight, half the waves; each load instr is a fully
//     coalesced lane-contiguous 1KB segment) + nontemporal load/store
//     (read-once/write-once streams; skip L2 allocate). Ideal traffic
//     268 MB => ~42 µs floor at 6.3-6.7 TB/s. If dur_us doesn't move,
//     kernel was already at floor and the rest is fixed harness overhead.

#define PE_D 1024
#define PE_S 4096
#define PE_B 8

typedef float f32x4 __attribute__((ext_vector_type(4)));

__global__ __launch_bounds__(256) void
PositionalEncoderModule_48455821033878_kernel(const float* __restrict__ x,
                                              float* __restrict__ out) {
    const int tid   = blockIdx.x * blockDim.x + threadIdx.x;  // 4,194,304
    const int lane  = tid & 63;
    const int chunk = tid >> 6;                // 128-float4 contiguous chunk
    const int fid0  = (chunk << 7) + lane;     // this thread's 1st float4
    // fid1 = fid0 + 64: wave's 2nd contiguous 1KB segment. Chunks are
    // 128-float4 aligned and a row is 256 float4, so both fall in one row.
    const int s     = (fid0 >> 8) & (PE_S - 1);
    const int d4a   = fid0 & (PE_D / 4 - 1);   // float4 idx within row

    const f32x4* px0 = (const f32x4*)x + fid0;
    f32x4* po0       = (f32x4*)out + fid0;

    // Issue both loads up front; pe math hides their latency.
    f32x4 v0 = __builtin_nontemporal_load(px0);
    f32x4 v1 = __builtin_nontemporal_load(px0 + 64);

    const float pos = (float)s;
    // 10000^(-2d/1024) = exp2(c*d), c = -2*log2(1e4)/1024
    const float c = -0.025952563241307517f;
    // fold 1/(2pi) into the exponent: -log2(2*pi)
    const float L = -2.6514961294723187f;

    const int d0a = d4a << 2;          // first dim of segment 0
    const int d0b = d0a + 256;         // first dim of segment 1 (+64 float4)

    f32x4 p0, p1;
#pragma unroll
    for (int j = 0; j < 4; ++j) {
        {
            const float wr = exp2f(fmaf(c, (float)(d0a + j), L)); // w/(2pi)
            const float n  = floorf(pos * wr);
            const float r  = fmaf(pos, wr, -n);   // exact-product fract
            p0[j] = (j & 1) ? __builtin_amdgcn_cosf(r)
                            : __builtin_amdgcn_sinf(r);
        }
        {
            const float wr = exp2f(fmaf(c, (float)(d0b + j), L));
            const float n  = floorf(pos * wr);
            const float r  = fmaf(pos, wr, -n);
            p1[j] = (j & 1) ? __builtin_amdgcn_cosf(r)
                            : __builtin_amdgcn_sinf(r);
        }
    }

    v0 += p0;
    v1 += p1;
    __builtin_nontemporal_store(v0, po0);
    __builtin_nontemporal_store(v1, po0 + 64);
}

extern "C" void kernel_launch(void* const* d_in, const int* in_sizes, int n_in,
                              void* d_out, int out_size, void* d_ws, size_t ws_size,
                              hipStream_t stream) {
    const float* x = (const float*)d_in[0];
    float* out     = (float*)d_out;

    const int n_threads = PE_B * PE_S * PE_D / 8;   // 4,194,304 (2 float4/thread)
    const int block = 256;
    const int grid  = n_threads / block;            // 16384

    PositionalEncoderModule_48455821033878_kernel<<<grid, block, 0, stream>>>(x, out);
}

// Round 3
// 217.189 us; speedup vs baseline: 1.0185x; 1.0053x over previous
//
#include <hip/hip_runtime.h>
#include <math.h>

// out[b,s,d] = x[b,s,d] + pe[s,d];  x: fp32 [8, 4096, 1024]
// pe[s,d] = sin(s * 10000^(-2d/1024)) if d even else cos(...)
//
// R1: batch-amortized pe, latency-bound (2 TB/s, VALUBusy 5%) — serialized
//     8 ld/st per thread with only 32 VGPRs.
// R2: max-TLP structure but hand-written chain constants were wrong at 1e-5
//     rel — ×4000 rad phase amplification → absmax 0.133 (fail).
// R3: R2 structure + per-element exp2f + libm sinf/cosf (passed, 220 µs).
// R4: hw trig (v_sin/v_cos in revolutions, exact-product fract) — dur_us
//     unchanged (221 µs) => kernel is NOT VALU-bound. Kernel absent from
//     duration-sorted top-5 (all ~80µs re-poison fills) => kernel itself
//     <80 µs; dur_us ≈ 2×80.5 µs harness fills + ~57 µs kernel.
// R5: 2 float4/thread + nontemporal ld/st: 221.2 -> 218.3 (-2.9 µs, edge
//     of noise but in the predicted direction). MLP lever seems live.
// R6 (this): push MLP harder — 4 float4/thread, ONE WAVE PER ROW:
//     64 lanes x 4 segs x 16B = 4KB = one row of D=1024. All 4 NT loads
//     issue back-to-back (4KB in flight before first dependent use);
//     segment offsets +1KB/+2KB/+3KB are compile-time imm offsets; s is
//     wave-uniform. pe math bit-identical to the passing R3-R5 path.
//     If dur_us doesn't move: kernel is at the 268MB/6.3TB/s ~43µs copy
//     floor and the rest is fixed harness fill/restore overhead => roofline.

#define PE_D 1024
#define PE_S 4096
#define PE_B 8

typedef float f32x4 __attribute__((ext_vector_type(4)));

__global__ __launch_bounds__(256) void
PositionalEncoderModule_48455821033878_kernel(const float* __restrict__ x,
                                              float* __restrict__ out) {
    const int tid  = blockIdx.x * blockDim.x + threadIdx.x;   // 2,097,152
    const int lane = tid & 63;
    const int row  = tid >> 6;                  // one wave <-> one [b,s] row
    const int s    = row & (PE_S - 1);

    // float4 index of this thread's segment-0 element
    const size_t fid0 = (size_t)row * (PE_D / 4) + lane;
    const f32x4* px   = (const f32x4*)x + fid0;
    f32x4* po         = (f32x4*)out + fid0;

    // Issue all 4 loads up front; +64/+128/+192 float4 = +1KB/+2KB/+3KB
    // compile-time offsets. pe math hides their latency.
    f32x4 v0 = __builtin_nontemporal_load(px);
    f32x4 v1 = __builtin_nontemporal_load(px + 64);
    f32x4 v2 = __builtin_nontemporal_load(px + 128);
    f32x4 v3 = __builtin_nontemporal_load(px + 192);

    const float pos = (float)s;
    // 10000^(-2d/1024) = exp2(c*d), c = -2*log2(1e4)/1024
    const float c = -0.025952563241307517f;
    // fold 1/(2pi) into the exponent: -log2(2*pi)
    const float L = -2.6514961294723187f;

    const int d0 = lane << 2;   // segment k adds k*256 dims

    f32x4 p0, p1, p2, p3;
#pragma unroll
    for (int j = 0; j < 4; ++j) {
        const bool odd = (j & 1);
#pragma unroll
        for (int k = 0; k < 4; ++k) {
            const float dd = (float)(d0 + k * 256 + j);
            const float wr = exp2f(fmaf(c, dd, L));   // w_d / (2pi)
            const float n  = floorf(pos * wr);
            const float r  = fmaf(pos, wr, -n);       // exact-product fract
            const float t  = odd ? __builtin_amdgcn_cosf(r)
                                 : __builtin_amdgcn_sinf(r);
            if      (k == 0) p0[j] = t;
            else if (k == 1) p1[j] = t;
            else if (k == 2) p2[j] = t;
            else             p3[j] = t;
        }
    }

    v0 += p0;
    v1 += p1;
    v2 += p2;
    v3 += p3;
    __builtin_nontemporal_store(v0, po);
    __builtin_nontemporal_store(v1, po + 64);
    __builtin_nontemporal_store(v2, po + 128);
    __builtin_nontemporal_store(v3, po + 192);
}

extern "C" void kernel_launch(void* const* d_in, const int* in_sizes, int n_in,
                              void* d_out, int out_size, void* d_ws, size_t ws_size,
                              hipStream_t stream) {
    const float* x = (const float*)d_in[0];
    float* out     = (float*)d_out;

    const int n_threads = PE_B * PE_S * PE_D / 16;  // 2,097,152 (4 float4/thread)
    const int block = 256;
    const int grid  = n_threads / block;            // 8192

    PositionalEncoderModule_48455821033878_kernel<<<grid, block, 0, stream>>>(x, out);
}